// Round 1
// baseline (349.452 us; speedup 1.0000x reference)
//
#include <hip/hip_runtime.h>
#include <math.h>

#define M_DIM 8192
#define K_DIM 2048
#define N_DIM 4096
#define TOPK  82

typedef short short8 __attribute__((ext_vector_type(8)));
typedef float f32x4 __attribute__((ext_vector_type(4)));
typedef unsigned short ushort_t;

__device__ __forceinline__ unsigned short f2bf(float f){
  unsigned u = __float_as_uint(f);
  unsigned r = (u + 0x7FFFu + ((u >> 16) & 1u)) >> 16;  // RNE; exact for 0.0/1.0
  return (unsigned short)r;
}

// ---------------- boost factor (fp64, once) ----------------
__global__ __launch_bounds__(256) void boost_kernel(const float* __restrict__ avg,
                                                    double* __restrict__ boost){
  __shared__ double sp[256];
  __shared__ double stot;
  int tid = threadIdx.x;
  double s = 0.0;
  for (int i = 0; i < 16; ++i) s += (double)avg[tid + 256*i];
  sp[tid] = s;
  __syncthreads();
  if (tid == 0){ double t = 0.0; for (int i = 0; i < 256; ++i) t += sp[i]; stot = t; }
  __syncthreads();
  double tot = stot;
  for (int i = 0; i < 16; ++i){
    int j = tid + 256*i;
    double a = (double)avg[j];
    double nb = (tot - a) / 4095.0;               // (total - avg)/(D-1)
    boost[j] = exp(-100.0 * (a - nb));
  }
}

// ---------------- A: fp32 -> bf16 (layout preserved [M][K]) ----------------
__global__ __launch_bounds__(256) void convA_kernel(const float* __restrict__ X,
                                                    ushort_t* __restrict__ Apre){
  size_t base = ((size_t)blockIdx.x * 256 + threadIdx.x) * 8;
  float4 f0 = *(const float4*)&X[base];
  float4 f1 = *(const float4*)&X[base + 4];
  uint4 u;
  u.x = (unsigned)f2bf(f0.x) | ((unsigned)f2bf(f0.y) << 16);
  u.y = (unsigned)f2bf(f0.z) | ((unsigned)f2bf(f0.w) << 16);
  u.z = (unsigned)f2bf(f1.x) | ((unsigned)f2bf(f1.y) << 16);
  u.w = (unsigned)f2bf(f1.z) | ((unsigned)f2bf(f1.w) << 16);
  *(uint4*)&Apre[base] = u;
}

// ---------------- B: fp32 [K][N] -> bf16 transposed [N][K] ----------------
__global__ __launch_bounds__(256) void convB_kernel(const float* __restrict__ Cn,
                                                    ushort_t* __restrict__ Bt){
  __shared__ float s[32][33];
  int tid = threadIdx.x;
  int bk = blockIdx.x & 63;        // K/32 = 64 tiles
  int bn = blockIdx.x >> 6;        // N/32 = 128 tiles
  int lr = tid >> 5, lc = tid & 31;
  for (int i = 0; i < 4; ++i)
    s[lr + 8*i][lc] = Cn[((size_t)(bk*32 + lr + 8*i))*N_DIM + bn*32 + lc];
  __syncthreads();
  for (int i = 0; i < 4; ++i)
    Bt[((size_t)(bn*32 + lr + 8*i))*K_DIM + bk*32 + lc] = f2bf(s[lc][lr + 8*i]);
}

// ---------------- GEMM: counts = x @ connection (exact ints in fp32) --------
// 128x128 tile, BK=32, 4 waves, mfma_f32_16x16x32_bf16.
// A frag: row = lane&15, k = (lane>>4)*8 + j   (K-contiguous b128 read)
// B frag: col = lane&15, k = (lane>>4)*8 + j   (from B^T layout [N][K])
// C/D   : col = lane&15, row = (lane>>4)*4 + reg   [m89-verified]
template<bool PRE>
__global__ __launch_bounds__(256) void gemm_kernel(const ushort_t* __restrict__ Apre,
                                                   const ushort_t* __restrict__ Bt,
                                                   const float* __restrict__ X,
                                                   const float* __restrict__ Cn,
                                                   float* __restrict__ out){
  __shared__ ushort_t As[128*32];
  __shared__ ushort_t Bs[128*32];   // Bs[col][k] (B^T tile)
  int tid = threadIdx.x;
  int bn = blockIdx.x & 31, bm = blockIdx.x >> 5;
  int brow = bm * 128, bcol = bn * 128;
  int lane = tid & 63, w = tid >> 6;
  int wr = w >> 1, wc = w & 1;
  int fr = lane & 15, fq = lane >> 4;
  f32x4 acc[4][4];
  for (int m = 0; m < 4; ++m)
    for (int n = 0; n < 4; ++n)
      acc[m][n] = (f32x4){0.f, 0.f, 0.f, 0.f};

  int r2 = tid >> 1, h = tid & 1;     // staging rows (PRE path + A fallback)
  int kr = tid >> 3, seg = tid & 7;   // B fallback staging

  for (int kk = 0; kk < K_DIM; kk += 32){
    __syncthreads();
    if constexpr (PRE){
      const ushort_t* ga = Apre + ((size_t)(brow + r2))*K_DIM + kk + h*16;
      *(uint4*)&As[r2*32 + h*16]     = *(const uint4*)(ga);
      *(uint4*)&As[r2*32 + h*16 + 8] = *(const uint4*)(ga + 8);
      const ushort_t* gb = Bt + ((size_t)(bcol + r2))*K_DIM + kk + h*16;
      *(uint4*)&Bs[r2*32 + h*16]     = *(const uint4*)(gb);
      *(uint4*)&Bs[r2*32 + h*16 + 8] = *(const uint4*)(gb + 8);
    } else {
      const float* ga = X + ((size_t)(brow + r2))*K_DIM + kk + h*16;
      unsigned pk[8];
      for (int q = 0; q < 4; ++q){
        float4 f = *(const float4*)(ga + q*4);
        pk[q*2]   = (unsigned)f2bf(f.x) | ((unsigned)f2bf(f.y) << 16);
        pk[q*2+1] = (unsigned)f2bf(f.z) | ((unsigned)f2bf(f.w) << 16);
      }
      uint4 u0; u0.x = pk[0]; u0.y = pk[1]; u0.z = pk[2]; u0.w = pk[3];
      uint4 u1; u1.x = pk[4]; u1.y = pk[5]; u1.z = pk[6]; u1.w = pk[7];
      *(uint4*)&As[r2*32 + h*16]     = u0;
      *(uint4*)&As[r2*32 + h*16 + 8] = u1;
      // B tile [32][128] -> transposed into Bs[col][k] via u16 scatter writes
      const float* gb = Cn + ((size_t)(kk + kr))*N_DIM + bcol + seg*16;
      for (int q = 0; q < 4; ++q){
        float4 f = *(const float4*)(gb + q*4);
        Bs[(seg*16 + q*4 + 0)*32 + kr] = f2bf(f.x);
        Bs[(seg*16 + q*4 + 1)*32 + kr] = f2bf(f.y);
        Bs[(seg*16 + q*4 + 2)*32 + kr] = f2bf(f.z);
        Bs[(seg*16 + q*4 + 3)*32 + kr] = f2bf(f.w);
      }
    }
    __syncthreads();
    short8 a[4], b[4];
    for (int m = 0; m < 4; ++m) a[m] = *(const short8*)&As[(wr*64 + m*16 + fr)*32 + fq*8];
    for (int n = 0; n < 4; ++n) b[n] = *(const short8*)&Bs[(wc*64 + n*16 + fr)*32 + fq*8];
    for (int m = 0; m < 4; ++m)
      for (int n = 0; n < 4; ++n)
        acc[m][n] = __builtin_amdgcn_mfma_f32_16x16x32_bf16(a[m], b[n], acc[m][n], 0, 0, 0);
  }
  for (int m = 0; m < 4; ++m)
    for (int n = 0; n < 4; ++n){
      int row = brow + wr*64 + m*16 + fq*4;
      int col = bcol + wc*64 + n*16 + fr;
      for (int j = 0; j < 4; ++j)
        out[((size_t)(row + j))*N_DIM + col] = acc[m][n][j];
    }
}

// ---------------- per-row exact top-82 -> one-hot (in-place on d_out) -------
// Radix-select: 4096-bin histogram on top-12 bits of float(val), then exact
// (double,idx) rank among boundary-bin candidates. Tie-break: lower idx wins
// (matches jax.lax.top_k stability).
__global__ __launch_bounds__(256) void topk_kernel(float* __restrict__ io,
                                                   const double* __restrict__ boost){
  __shared__ unsigned hist[4096];
  __shared__ unsigned pref[256];
  __shared__ double cval[1024];
  __shared__ int cidx[1024];
  __shared__ int sb, sk1, scnt;
  __shared__ double sTv;
  __shared__ int sTi;
  int tid = threadIdx.x;
  float* rp = io + (size_t)blockIdx.x * N_DIM;

  double v[16];
  unsigned bin[16];
  for (int g = 0; g < 4; ++g){
    float4 f = *(const float4*)&rp[g*1024 + tid*4];
    int c0 = g*1024 + tid*4;
    v[g*4+0] = (double)f.x * boost[c0+0];
    v[g*4+1] = (double)f.y * boost[c0+1];
    v[g*4+2] = (double)f.z * boost[c0+2];
    v[g*4+3] = (double)f.w * boost[c0+3];
  }
  for (int e = 0; e < 16; ++e) bin[e] = __float_as_uint((float)v[e]) >> 20;

  for (int i = 0; i < 16; ++i) hist[tid + 256*i] = 0u;
  if (tid == 0) scnt = 0;
  __syncthreads();
  for (int e = 0; e < 16; ++e) atomicAdd(&hist[bin[e]], 1u);
  __syncthreads();

  unsigned s = 0;
  for (int b = 0; b < 16; ++b) s += hist[tid*16 + b];
  pref[tid] = s;
  __syncthreads();
  for (int off = 1; off < 256; off <<= 1){          // inclusive suffix sums
    unsigned t2 = (tid + off < 256) ? pref[tid + off] : 0u;
    __syncthreads();
    pref[tid] += t2;
    __syncthreads();
  }
  unsigned St = pref[tid];
  unsigned Sn = (tid < 255) ? pref[tid + 1] : 0u;
  if (St >= TOPK && Sn < TOPK){                     // exactly one thread
    unsigned cum = Sn;
    for (int b = 15; b >= 0; --b){
      unsigned hb = hist[tid*16 + b];
      cum += hb;
      if (cum >= TOPK){ sb = tid*16 + b; sk1 = TOPK - (int)(cum - hb); break; }
    }
  }
  __syncthreads();
  unsigned bb = (unsigned)sb;
  int k1 = sk1;
  for (int e = 0; e < 16; ++e){
    if (bin[e] == bb){
      int pos = atomicAdd(&scnt, 1);
      if (pos < 1024){
        int g = e >> 2, j = e & 3;
        cval[pos] = v[e];
        cidx[pos] = g*1024 + tid*4 + j;
      }
    }
  }
  __syncthreads();
  int Csz = scnt; if (Csz > 1024) Csz = 1024;
  for (int i = tid; i < Csz; i += 256){
    double vi = cval[i]; int xi = cidx[i];
    int rk = 0;
    for (int j2 = 0; j2 < Csz; ++j2){
      double vj = cval[j2];
      rk += (int)((vj > vi) || (vj == vi && cidx[j2] < xi));
    }
    if (rk == k1 - 1){ sTv = vi; sTi = xi; }        // the exact 82nd element
  }
  __syncthreads();
  double Tv = sTv; int Ti = sTi;
  for (int g = 0; g < 4; ++g){
    int c0 = g*1024 + tid*4;
    float4 o;
    o.x = (v[g*4+0] > Tv || (v[g*4+0] == Tv && (c0+0) <= Ti)) ? 1.0f : 0.0f;
    o.y = (v[g*4+1] > Tv || (v[g*4+1] == Tv && (c0+1) <= Ti)) ? 1.0f : 0.0f;
    o.z = (v[g*4+2] > Tv || (v[g*4+2] == Tv && (c0+2) <= Ti)) ? 1.0f : 0.0f;
    o.w = (v[g*4+3] > Tv || (v[g*4+3] == Tv && (c0+3) <= Ti)) ? 1.0f : 0.0f;
    *(float4*)&rp[c0] = o;
  }
}

extern "C" void kernel_launch(void* const* d_in, const int* in_sizes, int n_in,
                              void* d_out, int out_size, void* d_ws, size_t ws_size,
                              hipStream_t stream){
  (void)in_sizes; (void)n_in; (void)out_size;
  const float* X   = (const float*)d_in[0];   // x [8192][2048]
  const float* Cn  = (const float*)d_in[1];   // connection [2048][4096]
  const float* avg = (const float*)d_in[2];   // avg_activation [4096]
  float* out = (float*)d_out;                 // [8192][4096]
  char* ws = (char*)d_ws;

  double* boost = (double*)ws;                              // 32 KB
  const size_t offA = 64 * 1024;
  ushort_t* Apre = (ushort_t*)(ws + offA);                  // 32 MB
  ushort_t* Bt   = (ushort_t*)(ws + offA + (size_t)33554432); // 16 MB
  const size_t need = offA + (size_t)33554432 + (size_t)16777216;
  bool pre = (ws_size >= need);

  boost_kernel<<<dim3(1), dim3(256), 0, stream>>>(avg, boost);
  if (pre){
    convA_kernel<<<dim3(8192), dim3(256), 0, stream>>>(X, Apre);
    convB_kernel<<<dim3(8192), dim3(256), 0, stream>>>(Cn, Bt);
    gemm_kernel<true><<<dim3(2048), dim3(256), 0, stream>>>(Apre, Bt, nullptr, nullptr, out);
  } else {
    gemm_kernel<false><<<dim3(2048), dim3(256), 0, stream>>>(nullptr, nullptr, X, Cn, out);
  }
  topk_kernel<<<dim3(8192), dim3(256), 0, stream>>>(out, boost);
}

// Round 2
// 258.179 us; speedup vs baseline: 1.3535x; 1.3535x over previous
//
#include <hip/hip_runtime.h>
#include <math.h>

#define M_DIM 8192
#define K_DIM 2048
#define N_DIM 4096
#define TOPK  82

typedef short short8 __attribute__((ext_vector_type(8)));
typedef float f32x4 __attribute__((ext_vector_type(4)));
typedef int   i32x4 __attribute__((ext_vector_type(4)));
typedef unsigned short ushort_t;

__device__ __forceinline__ unsigned short f2bf(float f){
  unsigned u = __float_as_uint(f);
  unsigned r = (u + 0x7FFFu + ((u >> 16) & 1u)) >> 16;  // RNE; exact for 0.0/1.0
  return (unsigned short)r;
}

// async global->LDS, 16B per lane. LDS dest = wave-uniform base + lane*16.
__device__ __forceinline__ void gload16(const void* g, void* l){
  __builtin_amdgcn_global_load_lds(
      (const __attribute__((address_space(1))) unsigned int*)g,
      (__attribute__((address_space(3))) unsigned int*)l,
      16, 0, 0);
}

// ---------------- boost factor (fp64, once) ----------------
__global__ __launch_bounds__(256) void boost_kernel(const float* __restrict__ avg,
                                                    double* __restrict__ boost){
  __shared__ double sp[4];
  __shared__ double stot;
  int tid = threadIdx.x;
  int lane = tid & 63, w = tid >> 6;
  double s = 0.0;
  for (int i = 0; i < 16; ++i) s += (double)avg[tid + 256*i];
  for (int off = 32; off > 0; off >>= 1) s += __shfl_down(s, off, 64);
  if (lane == 0) sp[w] = s;
  __syncthreads();
  if (tid == 0) stot = sp[0] + sp[1] + sp[2] + sp[3];
  __syncthreads();
  double tot = stot;
  for (int i = 0; i < 16; ++i){
    int j = tid + 256*i;
    double a = (double)avg[j];
    double nb = (tot - a) / 4095.0;               // (total - avg)/(D-1)
    boost[j] = exp(-100.0 * (a - nb));
  }
}

// ---------------- A: fp32 -> i8 (binary), layout preserved [M][K] ----------
__global__ __launch_bounds__(256) void convA8_kernel(const float* __restrict__ X,
                                                     unsigned char* __restrict__ A8){
  size_t base = ((size_t)blockIdx.x * 256 + threadIdx.x) * 16;
  unsigned r[4];
  for (int q = 0; q < 4; ++q){
    float4 f = *(const float4*)&X[base + q*4];
    r[q] = (unsigned)(f.x != 0.f) | ((unsigned)(f.y != 0.f) << 8)
         | ((unsigned)(f.z != 0.f) << 16) | ((unsigned)(f.w != 0.f) << 24);
  }
  uint4 o; o.x = r[0]; o.y = r[1]; o.z = r[2]; o.w = r[3];
  *(uint4*)&A8[base] = o;
}

// ---------------- B: fp32 [K][N] -> i8 transposed [N][K] --------------------
__global__ __launch_bounds__(256) void convB8_kernel(const float* __restrict__ Cn,
                                                     unsigned char* __restrict__ B8){
  __shared__ float s[32][33];
  int tid = threadIdx.x;
  int bk = blockIdx.x & 63;        // K/32 = 64 tiles
  int bn = blockIdx.x >> 6;        // N/32 = 128 tiles
  int lr = tid >> 5, lc = tid & 31;
  for (int i = 0; i < 4; ++i)
    s[lr + 8*i][lc] = Cn[((size_t)(bk*32 + lr + 8*i))*N_DIM + bn*32 + lc];
  __syncthreads();
  for (int i = 0; i < 4; ++i)
    B8[((size_t)(bn*32 + lr + 8*i))*K_DIM + bk*32 + lc] =
        (unsigned char)(s[lc][lr + 8*i] != 0.f);
}

// ---------------- i8 GEMM: counts = x @ connection (exact i32) -------------
// 128x128 tile, BK=128 (i8 bytes), 4 waves, mfma_i32_16x16x64_i8.
// LDS [row][8 slots of 16B], slot-swizzled: data for k-block kb of row r sits
// at slot kb^(r&7). global_load_lds writes linearly -> inverse-swizzle the
// per-lane GLOBAL source (rule #21: linear dest + inv-swz source + swz read).
// A frag: row = lane&15, k = (lane>>4)*16 + j (16 K-contiguous bytes/lane)
// C/D   : col = lane&15, row = (lane>>4)*4 + reg  [shape-determined, verified]
__global__ __launch_bounds__(256) void gemm8_kernel(const unsigned char* __restrict__ A8,
                                                    const unsigned char* __restrict__ B8,
                                                    float* __restrict__ out){
  __shared__ unsigned char As[16384];   // [128][128] swizzled
  __shared__ unsigned char Bs[16384];   // [col][128] swizzled (B^T tile)
  int tid = threadIdx.x;
  unsigned sw = ((unsigned)blockIdx.x & 7u)*256u + ((unsigned)blockIdx.x >> 3);  // XCD swizzle
  int bn = sw & 31, bm = sw >> 5;
  int brow = bm * 128, bcol = bn * 128;
  int lane = tid & 63, w = tid >> 6;
  int wr = w >> 1, wc = w & 1;
  int fr = lane & 15, fq = lane >> 4;
  int l8 = lane >> 3, slot = lane & 7;

  i32x4 acc[4][4];
  for (int m = 0; m < 4; ++m)
    for (int n = 0; n < 4; ++n)
      acc[m][n] = (i32x4){0, 0, 0, 0};

  for (int kk = 0; kk < K_DIM; kk += 128){
    __syncthreads();
    for (int q = 0; q < 4; ++q){
      int row = q*32 + w*8 + l8;
      int kb  = slot ^ (row & 7);
      gload16(A8 + ((size_t)(brow + row))*K_DIM + kk + kb*16,
              As + q*4096 + w*1024);
      gload16(B8 + ((size_t)(bcol + row))*K_DIM + kk + kb*16,
              Bs + q*4096 + w*1024);
    }
    __syncthreads();
    for (int ks = 0; ks < 2; ++ks){
      i32x4 a[4], b[4];
      for (int m = 0; m < 4; ++m){
        int row = wr*64 + m*16 + fr;
        int sl = (ks*4 + fq) ^ (row & 7);
        a[m] = *(const i32x4*)&As[row*128 + sl*16];
      }
      for (int n = 0; n < 4; ++n){
        int row = wc*64 + n*16 + fr;
        int sl = (ks*4 + fq) ^ (row & 7);
        b[n] = *(const i32x4*)&Bs[row*128 + sl*16];
      }
      for (int m = 0; m < 4; ++m)
        for (int n = 0; n < 4; ++n)
          acc[m][n] = __builtin_amdgcn_mfma_i32_16x16x64_i8(a[m], b[n], acc[m][n], 0, 0, 0);
    }
  }
  for (int m = 0; m < 4; ++m)
    for (int n = 0; n < 4; ++n){
      int row = brow + wr*64 + m*16 + fq*4;
      int col = bcol + wc*64 + n*16 + fr;
      for (int j = 0; j < 4; ++j)
        out[((size_t)(row + j))*N_DIM + col] = (float)acc[m][n][j];
    }
}

// ---------------- fallback GEMM (tiny ws): bf16 reg-staged ------------------
__global__ __launch_bounds__(256) void gemm_fb_kernel(const float* __restrict__ X,
                                                      const float* __restrict__ Cn,
                                                      float* __restrict__ out){
  __shared__ ushort_t As[128*32];
  __shared__ ushort_t Bs[128*32];
  int tid = threadIdx.x;
  int bn = blockIdx.x & 31, bm = blockIdx.x >> 5;
  int brow = bm * 128, bcol = bn * 128;
  int lane = tid & 63, w = tid >> 6;
  int wr = w >> 1, wc = w & 1;
  int fr = lane & 15, fq = lane >> 4;
  f32x4 acc[4][4];
  for (int m = 0; m < 4; ++m)
    for (int n = 0; n < 4; ++n)
      acc[m][n] = (f32x4){0.f, 0.f, 0.f, 0.f};
  int r2 = tid >> 1, h = tid & 1;
  int kr = tid >> 3, seg = tid & 7;
  for (int kk = 0; kk < K_DIM; kk += 32){
    __syncthreads();
    const float* ga = X + ((size_t)(brow + r2))*K_DIM + kk + h*16;
    unsigned pk[8];
    for (int q = 0; q < 4; ++q){
      float4 f = *(const float4*)(ga + q*4);
      pk[q*2]   = (unsigned)f2bf(f.x) | ((unsigned)f2bf(f.y) << 16);
      pk[q*2+1] = (unsigned)f2bf(f.z) | ((unsigned)f2bf(f.w) << 16);
    }
    uint4 u0; u0.x = pk[0]; u0.y = pk[1]; u0.z = pk[2]; u0.w = pk[3];
    uint4 u1; u1.x = pk[4]; u1.y = pk[5]; u1.z = pk[6]; u1.w = pk[7];
    *(uint4*)&As[r2*32 + h*16]     = u0;
    *(uint4*)&As[r2*32 + h*16 + 8] = u1;
    const float* gb = Cn + ((size_t)(kk + kr))*N_DIM + bcol + seg*16;
    for (int q = 0; q < 4; ++q){
      float4 f = *(const float4*)(gb + q*4);
      Bs[(seg*16 + q*4 + 0)*32 + kr] = f2bf(f.x);
      Bs[(seg*16 + q*4 + 1)*32 + kr] = f2bf(f.y);
      Bs[(seg*16 + q*4 + 2)*32 + kr] = f2bf(f.z);
      Bs[(seg*16 + q*4 + 3)*32 + kr] = f2bf(f.w);
    }
    __syncthreads();
    short8 a[4], b[4];
    for (int m = 0; m < 4; ++m) a[m] = *(const short8*)&As[(wr*64 + m*16 + fr)*32 + fq*8];
    for (int n = 0; n < 4; ++n) b[n] = *(const short8*)&Bs[(wc*64 + n*16 + fr)*32 + fq*8];
    for (int m = 0; m < 4; ++m)
      for (int n = 0; n < 4; ++n)
        acc[m][n] = __builtin_amdgcn_mfma_f32_16x16x32_bf16(a[m], b[n], acc[m][n], 0, 0, 0);
  }
  for (int m = 0; m < 4; ++m)
    for (int n = 0; n < 4; ++n){
      int row = brow + wr*64 + m*16 + fq*4;
      int col = bcol + wc*64 + n*16 + fr;
      for (int j = 0; j < 4; ++j)
        out[((size_t)(row + j))*N_DIM + col] = acc[m][n][j];
    }
}

// ---------------- per-row exact top-82 -> one-hot (in-place on d_out) -------
__global__ __launch_bounds__(256) void topk_kernel(float* __restrict__ io,
                                                   const double* __restrict__ boost){
  __shared__ unsigned hist[4096];
  __shared__ unsigned pref[256];
  __shared__ double cval[1024];
  __shared__ int cidx[1024];
  __shared__ int sb, sk1, scnt;
  __shared__ double sTv;
  __shared__ int sTi;
  int tid = threadIdx.x;
  float* rp = io + (size_t)blockIdx.x * N_DIM;

  double v[16];
  unsigned bin[16];
  for (int g = 0; g < 4; ++g){
    float4 f = *(const float4*)&rp[g*1024 + tid*4];
    int c0 = g*1024 + tid*4;
    v[g*4+0] = (double)f.x * boost[c0+0];
    v[g*4+1] = (double)f.y * boost[c0+1];
    v[g*4+2] = (double)f.z * boost[c0+2];
    v[g*4+3] = (double)f.w * boost[c0+3];
  }
  for (int e = 0; e < 16; ++e) bin[e] = __float_as_uint((float)v[e]) >> 20;

  for (int i = 0; i < 16; ++i) hist[tid + 256*i] = 0u;
  if (tid == 0) scnt = 0;
  __syncthreads();
  for (int e = 0; e < 16; ++e) atomicAdd(&hist[bin[e]], 1u);
  __syncthreads();

  unsigned s = 0;
  for (int b = 0; b < 16; ++b) s += hist[tid*16 + b];
  pref[tid] = s;
  __syncthreads();
  for (int off = 1; off < 256; off <<= 1){          // inclusive suffix sums
    unsigned t2 = (tid + off < 256) ? pref[tid + off] : 0u;
    __syncthreads();
    pref[tid] += t2;
    __syncthreads();
  }
  unsigned St = pref[tid];
  unsigned Sn = (tid < 255) ? pref[tid + 1] : 0u;
  if (St >= TOPK && Sn < TOPK){                     // exactly one thread
    unsigned cum = Sn;
    for (int b = 15; b >= 0; --b){
      unsigned hb = hist[tid*16 + b];
      cum += hb;
      if (cum >= TOPK){ sb = tid*16 + b; sk1 = TOPK - (int)(cum - hb); break; }
    }
  }
  __syncthreads();
  unsigned bb = (unsigned)sb;
  int k1 = sk1;
  for (int e = 0; e < 16; ++e){
    if (bin[e] == bb){
      int pos = atomicAdd(&scnt, 1);
      if (pos < 1024){
        int g = e >> 2, j = e & 3;
        cval[pos] = v[e];
        cidx[pos] = g*1024 + tid*4 + j;
      }
    }
  }
  __syncthreads();
  int Csz = scnt; if (Csz > 1024) Csz = 1024;
  for (int i = tid; i < Csz; i += 256){
    double vi = cval[i]; int xi = cidx[i];
    int rk = 0;
    for (int j2 = 0; j2 < Csz; ++j2){
      double vj = cval[j2];
      rk += (int)((vj > vi) || (vj == vi && cidx[j2] < xi));
    }
    if (rk == k1 - 1){ sTv = vi; sTi = xi; }        // the exact 82nd element
  }
  __syncthreads();
  double Tv = sTv; int Ti = sTi;
  for (int g = 0; g < 4; ++g){
    int c0 = g*1024 + tid*4;
    float4 o;
    o.x = (v[g*4+0] > Tv || (v[g*4+0] == Tv && (c0+0) <= Ti)) ? 1.0f : 0.0f;
    o.y = (v[g*4+1] > Tv || (v[g*4+1] == Tv && (c0+1) <= Ti)) ? 1.0f : 0.0f;
    o.z = (v[g*4+2] > Tv || (v[g*4+2] == Tv && (c0+2) <= Ti)) ? 1.0f : 0.0f;
    o.w = (v[g*4+3] > Tv || (v[g*4+3] == Tv && (c0+3) <= Ti)) ? 1.0f : 0.0f;
    *(float4*)&rp[c0] = o;
  }
}

extern "C" void kernel_launch(void* const* d_in, const int* in_sizes, int n_in,
                              void* d_out, int out_size, void* d_ws, size_t ws_size,
                              hipStream_t stream){
  (void)in_sizes; (void)n_in; (void)out_size;
  const float* X   = (const float*)d_in[0];   // x [8192][2048]
  const float* Cn  = (const float*)d_in[1];   // connection [2048][4096]
  const float* avg = (const float*)d_in[2];   // avg_activation [4096]
  float* out = (float*)d_out;                 // [8192][4096]
  char* ws = (char*)d_ws;

  double* boost = (double*)ws;                              // 32 KB
  const size_t offA = 64 * 1024;
  unsigned char* A8 = (unsigned char*)(ws + offA);                      // 16 MB
  unsigned char* B8 = (unsigned char*)(ws + offA + (size_t)16777216);   //  8 MB
  const size_t need = offA + (size_t)16777216 + (size_t)8388608;

  boost_kernel<<<dim3(1), dim3(256), 0, stream>>>(avg, boost);
  if (ws_size >= need){
    convA8_kernel<<<dim3(4096), dim3(256), 0, stream>>>(X, A8);
    convB8_kernel<<<dim3(8192), dim3(256), 0, stream>>>(Cn, B8);
    gemm8_kernel<<<dim3(2048), dim3(256), 0, stream>>>(A8, B8, out);
  } else {
    gemm_fb_kernel<<<dim3(2048), dim3(256), 0, stream>>>(X, Cn, out);
  }
  topk_kernel<<<dim3(8192), dim3(256), 0, stream>>>(out, boost);
}

// Round 3
// 190.995 us; speedup vs baseline: 1.8296x; 1.3518x over previous
//
#include <hip/hip_runtime.h>
#include <math.h>

#define M_DIM 8192
#define K_DIM 2048
#define N_DIM 4096
#define TOPK  82

typedef short short8 __attribute__((ext_vector_type(8)));
typedef float f32x4 __attribute__((ext_vector_type(4)));
typedef int   i32x4 __attribute__((ext_vector_type(4)));
typedef unsigned short ushort_t;
typedef unsigned long long u64;

__device__ __forceinline__ unsigned short f2bf(float f){
  unsigned u = __float_as_uint(f);
  unsigned r = (u + 0x7FFFu + ((u >> 16) & 1u)) >> 16;  // RNE; exact for 0.0/1.0
  return (unsigned short)r;
}

// async global->LDS, 16B per lane. LDS dest = wave-uniform base + lane*16.
__device__ __forceinline__ void gload16(const void* g, void* l){
  __builtin_amdgcn_global_load_lds(
      (const __attribute__((address_space(1))) unsigned int*)g,
      (__attribute__((address_space(3))) unsigned int*)l,
      16, 0, 0);
}

// ---------------- boost factor (fp64, once) ----------------
__global__ __launch_bounds__(256) void boost_kernel(const float* __restrict__ avg,
                                                    double* __restrict__ boost){
  __shared__ double sp[4];
  __shared__ double stot;
  int tid = threadIdx.x;
  int lane = tid & 63, w = tid >> 6;
  double s = 0.0;
  for (int i = 0; i < 16; ++i) s += (double)avg[tid + 256*i];
  for (int off = 32; off > 0; off >>= 1) s += __shfl_down(s, off, 64);
  if (lane == 0) sp[w] = s;
  __syncthreads();
  if (tid == 0) stot = sp[0] + sp[1] + sp[2] + sp[3];
  __syncthreads();
  double tot = stot;
  for (int i = 0; i < 16; ++i){
    int j = tid + 256*i;
    double a = (double)avg[j];
    double nb = (tot - a) / 4095.0;               // (total - avg)/(D-1)
    boost[j] = exp(-100.0 * (a - nb));
  }
}

// ---------------- A: fp32 -> i8 (binary), layout preserved [M][K] ----------
__global__ __launch_bounds__(256) void convA8_kernel(const float* __restrict__ X,
                                                     unsigned char* __restrict__ A8){
  size_t base = ((size_t)blockIdx.x * 256 + threadIdx.x) * 16;
  unsigned r[4];
  for (int q = 0; q < 4; ++q){
    float4 f = *(const float4*)&X[base + q*4];
    r[q] = (unsigned)(f.x != 0.f) | ((unsigned)(f.y != 0.f) << 8)
         | ((unsigned)(f.z != 0.f) << 16) | ((unsigned)(f.w != 0.f) << 24);
  }
  uint4 o; o.x = r[0]; o.y = r[1]; o.z = r[2]; o.w = r[3];
  *(uint4*)&A8[base] = o;
}

// ---------------- B: fp32 [K][N] -> i8 transposed [N][K] --------------------
__global__ __launch_bounds__(256) void convB8_kernel(const float* __restrict__ Cn,
                                                     unsigned char* __restrict__ B8){
  __shared__ float s[32][33];
  int tid = threadIdx.x;
  int bk = blockIdx.x & 63;        // K/32 = 64 tiles
  int bn = blockIdx.x >> 6;        // N/32 = 128 tiles
  int lr = tid >> 5, lc = tid & 31;
  for (int i = 0; i < 4; ++i)
    s[lr + 8*i][lc] = Cn[((size_t)(bk*32 + lr + 8*i))*N_DIM + bn*32 + lc];
  __syncthreads();
  for (int i = 0; i < 4; ++i)
    B8[((size_t)(bn*32 + lr + 8*i))*K_DIM + bk*32 + lc] =
        (unsigned char)(s[lc][lr + 8*i] != 0.f);
}

// ---------------- i8 GEMM: counts = x @ connection (exact i32) -------------
__global__ __launch_bounds__(256) void gemm8_kernel(const unsigned char* __restrict__ A8,
                                                    const unsigned char* __restrict__ B8,
                                                    float* __restrict__ out){
  __shared__ unsigned char As[16384];   // [128][128] swizzled
  __shared__ unsigned char Bs[16384];   // [col][128] swizzled (B^T tile)
  int tid = threadIdx.x;
  unsigned sw = ((unsigned)blockIdx.x & 7u)*256u + ((unsigned)blockIdx.x >> 3);  // XCD swizzle
  int bn = sw & 31, bm = sw >> 5;
  int brow = bm * 128, bcol = bn * 128;
  int lane = tid & 63, w = tid >> 6;
  int wr = w >> 1, wc = w & 1;
  int fr = lane & 15, fq = lane >> 4;
  int l8 = lane >> 3, slot = lane & 7;

  i32x4 acc[4][4];
  for (int m = 0; m < 4; ++m)
    for (int n = 0; n < 4; ++n)
      acc[m][n] = (i32x4){0, 0, 0, 0};

  for (int kk = 0; kk < K_DIM; kk += 128){
    __syncthreads();
    for (int q = 0; q < 4; ++q){
      int row = q*32 + w*8 + l8;
      int kb  = slot ^ (row & 7);
      gload16(A8 + ((size_t)(brow + row))*K_DIM + kk + kb*16,
              As + q*4096 + w*1024);
      gload16(B8 + ((size_t)(bcol + row))*K_DIM + kk + kb*16,
              Bs + q*4096 + w*1024);
    }
    __syncthreads();
    for (int ks = 0; ks < 2; ++ks){
      i32x4 a[4], b[4];
      for (int m = 0; m < 4; ++m){
        int row = wr*64 + m*16 + fr;
        int sl = (ks*4 + fq) ^ (row & 7);
        a[m] = *(const i32x4*)&As[row*128 + sl*16];
      }
      for (int n = 0; n < 4; ++n){
        int row = wc*64 + n*16 + fr;
        int sl = (ks*4 + fq) ^ (row & 7);
        b[n] = *(const i32x4*)&Bs[row*128 + sl*16];
      }
      for (int m = 0; m < 4; ++m)
        for (int n = 0; n < 4; ++n)
          acc[m][n] = __builtin_amdgcn_mfma_i32_16x16x64_i8(a[m], b[n], acc[m][n], 0, 0, 0);
    }
  }
  for (int m = 0; m < 4; ++m)
    for (int n = 0; n < 4; ++n){
      int row = brow + wr*64 + m*16 + fq*4;
      int col = bcol + wc*64 + n*16 + fr;
      for (int j = 0; j < 4; ++j)
        out[((size_t)(row + j))*N_DIM + col] = (float)acc[m][n][j];
    }
}

// ---------------- fallback GEMM (tiny ws): bf16 reg-staged ------------------
__global__ __launch_bounds__(256) void gemm_fb_kernel(const float* __restrict__ X,
                                                      const float* __restrict__ Cn,
                                                      float* __restrict__ out){
  __shared__ ushort_t As[128*32];
  __shared__ ushort_t Bs[128*32];
  int tid = threadIdx.x;
  int bn = blockIdx.x & 31, bm = blockIdx.x >> 5;
  int brow = bm * 128, bcol = bn * 128;
  int lane = tid & 63, w = tid >> 6;
  int wr = w >> 1, wc = w & 1;
  int fr = lane & 15, fq = lane >> 4;
  f32x4 acc[4][4];
  for (int m = 0; m < 4; ++m)
    for (int n = 0; n < 4; ++n)
      acc[m][n] = (f32x4){0.f, 0.f, 0.f, 0.f};
  int r2 = tid >> 1, h = tid & 1;
  int kr = tid >> 3, seg = tid & 7;
  for (int kk = 0; kk < K_DIM; kk += 32){
    __syncthreads();
    const float* ga = X + ((size_t)(brow + r2))*K_DIM + kk + h*16;
    unsigned pk[8];
    for (int q = 0; q < 4; ++q){
      float4 f = *(const float4*)(ga + q*4);
      pk[q*2]   = (unsigned)f2bf(f.x) | ((unsigned)f2bf(f.y) << 16);
      pk[q*2+1] = (unsigned)f2bf(f.z) | ((unsigned)f2bf(f.w) << 16);
    }
    uint4 u0; u0.x = pk[0]; u0.y = pk[1]; u0.z = pk[2]; u0.w = pk[3];
    uint4 u1; u1.x = pk[4]; u1.y = pk[5]; u1.z = pk[6]; u1.w = pk[7];
    *(uint4*)&As[r2*32 + h*16]     = u0;
    *(uint4*)&As[r2*32 + h*16 + 8] = u1;
    const float* gb = Cn + ((size_t)(kk + kr))*N_DIM + bcol + seg*16;
    for (int q = 0; q < 4; ++q){
      float4 f = *(const float4*)(gb + q*4);
      Bs[(seg*16 + q*4 + 0)*32 + kr] = f2bf(f.x);
      Bs[(seg*16 + q*4 + 1)*32 + kr] = f2bf(f.y);
      Bs[(seg*16 + q*4 + 2)*32 + kr] = f2bf(f.z);
      Bs[(seg*16 + q*4 + 3)*32 + kr] = f2bf(f.w);
    }
    __syncthreads();
    short8 a[4], b[4];
    for (int m = 0; m < 4; ++m) a[m] = *(const short8*)&As[(wr*64 + m*16 + fr)*32 + fq*8];
    for (int n = 0; n < 4; ++n) b[n] = *(const short8*)&Bs[(wc*64 + n*16 + fr)*32 + fq*8];
    for (int m = 0; m < 4; ++m)
      for (int n = 0; n < 4; ++n)
        acc[m][n] = __builtin_amdgcn_mfma_f32_16x16x32_bf16(a[m], b[n], acc[m][n], 0, 0, 0);
  }
  for (int m = 0; m < 4; ++m)
    for (int n = 0; n < 4; ++n){
      int row = brow + wr*64 + m*16 + fq*4;
      int col = bcol + wc*64 + n*16 + fr;
      for (int j = 0; j < 4; ++j)
        out[((size_t)(row + j))*N_DIM + col] = acc[m][n][j];
    }
}

// ---------------- per-row exact top-82 -> one-hot (in-place on d_out) -------
// Two-level radix select on the DOUBLE bit pattern (positive doubles: value
// order == u64 bit order, so binning is exact — no float-rounding edge cases).
// L1: 4096 bins on bits[62:51]; L2: 4096 bins on bits[50:39] of boundary-bin
// members. Survivors share 24 leading bits -> typically 1-3 -> O(Csz^2) refine
// is trivial. Tie-break: lower index wins (jax.lax.top_k stability).

// Block-wide suffix-select over a 4096-bin LDS histogram: finds bin *pB such
// that count(bins > *pB) < Kt <= count(bins >= *pB); *pK = Kt - count(bins > *pB).
// Uses wave shfl suffix-scan + 4-entry cross-wave combine. 2 barriers.
__device__ __forceinline__ void find_bin(unsigned* hist, unsigned* wtot,
                                         int* pB, int* pK, int tid, int Kt){
  int lane = tid & 63, w = tid >> 6;
  unsigned s = 0;
  #pragma unroll
  for (int b = 0; b < 16; ++b) s += hist[tid*16 + b];
  unsigned S = s;
  #pragma unroll
  for (int off = 1; off < 64; off <<= 1){
    unsigned T = __shfl_down(S, off, 64);
    if (lane + off < 64) S += T;
  }
  if (lane == 0) wtot[w] = S;          // whole-wave total (suffix at lane 0)
  __syncthreads();
  unsigned above = 0;
  for (int w2 = w + 1; w2 < 4; ++w2) above += wtot[w2];
  unsigned St = S + above;             // count with bin >= tid*16
  unsigned Sn = St - s;                // count with bin >= (tid+1)*16
  if (St >= (unsigned)Kt && Sn < (unsigned)Kt){   // exactly one thread
    unsigned cum = Sn;
    for (int b = 15; b >= 0; --b){
      unsigned hb = hist[tid*16 + b];
      cum += hb;
      if (cum >= (unsigned)Kt){ *pB = tid*16 + b; *pK = Kt - (int)(cum - hb); break; }
    }
  }
  __syncthreads();
}

__global__ __launch_bounds__(256) void topk_kernel(float* __restrict__ io,
                                                   const double* __restrict__ boost){
  __shared__ unsigned hist[4096];
  __shared__ unsigned wtot[4];
  __shared__ int sB, sK, sB2, sK2, scnt, sTi;
  __shared__ u64 sTv;
  __shared__ u64 cbits[256];
  __shared__ int cidx[256];
  int tid = threadIdx.x;
  float* rp = io + (size_t)blockIdx.x * N_DIM;

  double v[16];
  unsigned bin[16];
  #pragma unroll
  for (int g = 0; g < 4; ++g){
    float4 f = *(const float4*)&rp[g*1024 + tid*4];
    double4 bf = *(const double4*)&boost[g*1024 + tid*4];
    v[g*4+0] = (double)f.x * bf.x;
    v[g*4+1] = (double)f.y * bf.y;
    v[g*4+2] = (double)f.z * bf.z;
    v[g*4+3] = (double)f.w * bf.w;
  }
  #pragma unroll
  for (int e = 0; e < 16; ++e)
    bin[e] = (unsigned)(((u64)__double_as_longlong(v[e])) >> 51) & 4095u;

  #pragma unroll
  for (int i = 0; i < 16; ++i) hist[tid + 256*i] = 0u;
  __syncthreads();
  #pragma unroll
  for (int e = 0; e < 16; ++e) atomicAdd(&hist[bin[e]], 1u);
  __syncthreads();

  find_bin(hist, wtot, &sB, &sK, tid, TOPK);       // L1: boundary bin B, rank k1
  int B = sB, k1 = sK;

  #pragma unroll
  for (int i = 0; i < 16; ++i) hist[tid + 256*i] = 0u;
  if (tid == 0) scnt = 0;
  __syncthreads();
  #pragma unroll
  for (int e = 0; e < 16; ++e){
    if (bin[e] == (unsigned)B){
      unsigned b2 = (unsigned)(((u64)__double_as_longlong(v[e])) >> 39) & 4095u;
      atomicAdd(&hist[b2], 1u);
    }
  }
  __syncthreads();

  find_bin(hist, wtot, &sB2, &sK2, tid, k1);       // L2: sub-bin B2, rank k2
  int B2 = sB2, k2 = sK2;

  #pragma unroll
  for (int e = 0; e < 16; ++e){
    if (bin[e] == (unsigned)B){
      u64 ub = (u64)__double_as_longlong(v[e]);
      if ((unsigned)((ub >> 39) & 4095u) == (unsigned)B2){
        int pos = atomicAdd(&scnt, 1);
        if (pos < 256){
          int g = e >> 2, j = e & 3;
          cbits[pos] = ub;
          cidx[pos] = g*1024 + tid*4 + j;
        }
      }
    }
  }
  __syncthreads();
  int Csz = scnt; if (Csz > 256) Csz = 256;
  for (int i = tid; i < Csz; i += 256){
    u64 bi = cbits[i]; int xi = cidx[i];
    int rk = 0;
    for (int j2 = 0; j2 < Csz; ++j2){
      u64 bj = cbits[j2];
      rk += (int)((bj > bi) || (bj == bi && cidx[j2] < xi));
    }
    if (rk == k2 - 1){ sTv = bi; sTi = xi; }       // the exact K-th element
  }
  __syncthreads();
  double Tv = __longlong_as_double((long long)sTv);
  int Ti = sTi;
  #pragma unroll
  for (int g = 0; g < 4; ++g){
    int c0 = g*1024 + tid*4;
    float4 o;
    o.x = (v[g*4+0] > Tv || (v[g*4+0] == Tv && (c0+0) <= Ti)) ? 1.0f : 0.0f;
    o.y = (v[g*4+1] > Tv || (v[g*4+1] == Tv && (c0+1) <= Ti)) ? 1.0f : 0.0f;
    o.z = (v[g*4+2] > Tv || (v[g*4+2] == Tv && (c0+2) <= Ti)) ? 1.0f : 0.0f;
    o.w = (v[g*4+3] > Tv || (v[g*4+3] == Tv && (c0+3) <= Ti)) ? 1.0f : 0.0f;
    *(float4*)&rp[c0] = o;
  }
}

extern "C" void kernel_launch(void* const* d_in, const int* in_sizes, int n_in,
                              void* d_out, int out_size, void* d_ws, size_t ws_size,
                              hipStream_t stream){
  (void)in_sizes; (void)n_in; (void)out_size;
  const float* X   = (const float*)d_in[0];   // x [8192][2048]
  const float* Cn  = (const float*)d_in[1];   // connection [2048][4096]
  const float* avg = (const float*)d_in[2];   // avg_activation [4096]
  float* out = (float*)d_out;                 // [8192][4096]
  char* ws = (char*)d_ws;

  double* boost = (double*)ws;                              // 32 KB
  const size_t offA = 64 * 1024;
  unsigned char* A8 = (unsigned char*)(ws + offA);                      // 16 MB
  unsigned char* B8 = (unsigned char*)(ws + offA + (size_t)16777216);   //  8 MB
  const size_t need = offA + (size_t)16777216 + (size_t)8388608;

  boost_kernel<<<dim3(1), dim3(256), 0, stream>>>(avg, boost);
  if (ws_size >= need){
    convA8_kernel<<<dim3(4096), dim3(256), 0, stream>>>(X, A8);
    convB8_kernel<<<dim3(8192), dim3(256), 0, stream>>>(Cn, B8);
    gemm8_kernel<<<dim3(2048), dim3(256), 0, stream>>>(A8, B8, out);
  } else {
    gemm_fb_kernel<<<dim3(2048), dim3(256), 0, stream>>>(X, Cn, out);
  }
  topk_kernel<<<dim3(8192), dim3(256), 0, stream>>>(out, boost);
}

// Round 4
// 170.993 us; speedup vs baseline: 2.0437x; 1.1170x over previous
//
#include <hip/hip_runtime.h>
#include <math.h>

#define M_DIM 8192
#define K_DIM 2048
#define N_DIM 4096
#define TOPK  82

typedef short short8 __attribute__((ext_vector_type(8)));
typedef float f32x4 __attribute__((ext_vector_type(4)));
typedef int   i32x4 __attribute__((ext_vector_type(4)));
typedef unsigned short ushort_t;
typedef unsigned long long u64;

__device__ __forceinline__ unsigned short f2bf(float f){
  unsigned u = __float_as_uint(f);
  unsigned r = (u + 0x7FFFu + ((u >> 16) & 1u)) >> 16;  // RNE; exact for 0.0/1.0
  return (unsigned short)r;
}

// async global->LDS, 16B per lane. LDS dest = wave-uniform base + lane*16.
__device__ __forceinline__ void gload16(const void* g, void* l){
  __builtin_amdgcn_global_load_lds(
      (const __attribute__((address_space(1))) unsigned int*)g,
      (__attribute__((address_space(3))) unsigned int*)l,
      16, 0, 0);
}

// ---------------- boost factor (fp64, once) ----------------
__global__ __launch_bounds__(256) void boost_kernel(const float* __restrict__ avg,
                                                    double* __restrict__ boost){
  __shared__ double sp[4];
  __shared__ double stot;
  int tid = threadIdx.x;
  int lane = tid & 63, w = tid >> 6;
  double s = 0.0;
  for (int i = 0; i < 16; ++i) s += (double)avg[tid + 256*i];
  for (int off = 32; off > 0; off >>= 1) s += __shfl_down(s, off, 64);
  if (lane == 0) sp[w] = s;
  __syncthreads();
  if (tid == 0) stot = sp[0] + sp[1] + sp[2] + sp[3];
  __syncthreads();
  double tot = stot;
  for (int i = 0; i < 16; ++i){
    int j = tid + 256*i;
    double a = (double)avg[j];
    double nb = (tot - a) / 4095.0;               // (total - avg)/(D-1)
    boost[j] = exp(-100.0 * (a - nb));
  }
}

// ---------------- A: fp32 -> i8 (binary), layout preserved [M][K] ----------
__global__ __launch_bounds__(256) void convA8_kernel(const float* __restrict__ X,
                                                     unsigned char* __restrict__ A8){
  size_t base = ((size_t)blockIdx.x * 256 + threadIdx.x) * 16;
  unsigned r[4];
  for (int q = 0; q < 4; ++q){
    float4 f = *(const float4*)&X[base + q*4];
    r[q] = (unsigned)(f.x != 0.f) | ((unsigned)(f.y != 0.f) << 8)
         | ((unsigned)(f.z != 0.f) << 16) | ((unsigned)(f.w != 0.f) << 24);
  }
  uint4 o; o.x = r[0]; o.y = r[1]; o.z = r[2]; o.w = r[3];
  *(uint4*)&A8[base] = o;
}

// ---------------- B: fp32 [K][N] -> i8 transposed [N][K] --------------------
__global__ __launch_bounds__(256) void convB8_kernel(const float* __restrict__ Cn,
                                                     unsigned char* __restrict__ B8){
  __shared__ float s[32][33];
  int tid = threadIdx.x;
  int bk = blockIdx.x & 63;        // K/32 = 64 tiles
  int bn = blockIdx.x >> 6;        // N/32 = 128 tiles
  int lr = tid >> 5, lc = tid & 31;
  for (int i = 0; i < 4; ++i)
    s[lr + 8*i][lc] = Cn[((size_t)(bk*32 + lr + 8*i))*N_DIM + bn*32 + lc];
  __syncthreads();
  for (int i = 0; i < 4; ++i)
    B8[((size_t)(bn*32 + lr + 8*i))*K_DIM + bk*32 + lc] =
        (unsigned char)(s[lc][lr + 8*i] != 0.f);
}

// ---------------- i8 GEMM, 256x256 tile, 2-phase double-buffered ------------
// BK=128 bytes, 8 waves (2M x 4N), mfma_i32_16x16x64_i8.
// T3-minimum schedule: STAGE(next tile, buf^1) issued BEFORE compute of the
// current tile; single (compiler-emitted) vmcnt(0)+barrier per K-tile, so HBM
// latency hides under ~2500 cycles of MFMA+ds_read.
// LDS 8-slot XOR swizzle identical to the verified round-2/3 kernel
// (linear gload_lds dest + inverse-swizzled global source + swizzled ds_read).
// u16 epilogue stages the 256x256 counts tile in the freed 128 KB LDS for
// fully-coalesced 16B global stores (avoids 32B-segment write amplification).
template<typename OUT_T>
__global__ __launch_bounds__(512, 2) void gemm2_kernel(const unsigned char* __restrict__ A8,
                                                       const unsigned char* __restrict__ B8,
                                                       OUT_T* __restrict__ out){
  __shared__ unsigned char smem[131072];   // [2][32KB] A | [2][32KB] B; epilogue: u16[256][256]
  int tid = threadIdx.x;
  int lane = tid & 63, w = tid >> 6;
  unsigned bid = blockIdx.x;
  unsigned sw = (bid & 7u)*64u + (bid >> 3);   // XCD swizzle, 512%8==0 -> bijective
  int bn = sw & 15, bm = sw >> 4;
  int brow = bm*256, bcol = bn*256;
  int wr = w >> 2, wc = w & 3;
  int fr = lane & 15, fq = lane >> 4;
  int l8 = lane >> 3, slot = lane & 7;

  i32x4 acc[8][4];
  #pragma unroll
  for (int m = 0; m < 8; ++m)
    #pragma unroll
    for (int n = 0; n < 4; ++n) acc[m][n] = (i32x4){0,0,0,0};

  auto stage = [&](int c, int kt){
    unsigned char* As = smem + c*32768;
    unsigned char* Bs = smem + 65536 + c*32768;
    int kk = kt*128;
    #pragma unroll
    for (int q = 0; q < 4; ++q){
      int row = q*64 + w*8 + l8;
      int kb = slot ^ (row & 7);
      gload16(A8 + ((size_t)(brow+row))*K_DIM + kk + kb*16, As + q*8192 + w*1024);
      gload16(B8 + ((size_t)(bcol+row))*K_DIM + kk + kb*16, Bs + q*8192 + w*1024);
    }
  };

  stage(0, 0);
  __syncthreads();                 // compiler emits vmcnt(0) before s_barrier
  int cur = 0;
  for (int kt = 0; kt < 16; ++kt){
    if (kt < 15) stage(cur ^ 1, kt + 1);     // prefetch flies under compute
    const unsigned char* As = smem + cur*32768;
    const unsigned char* Bs = smem + 65536 + cur*32768;
    #pragma unroll
    for (int ks = 0; ks < 2; ++ks){
      i32x4 b[4];
      #pragma unroll
      for (int n = 0; n < 4; ++n){
        int row = wc*64 + n*16 + fr;
        int sl = (ks*4 + fq) ^ (row & 7);
        b[n] = *(const i32x4*)&Bs[row*128 + sl*16];
      }
      #pragma unroll
      for (int mh = 0; mh < 2; ++mh){
        i32x4 a[4];
        #pragma unroll
        for (int mi = 0; mi < 4; ++mi){
          int row = wr*128 + (mh*4 + mi)*16 + fr;
          int sl = (ks*4 + fq) ^ (row & 7);
          a[mi] = *(const i32x4*)&As[row*128 + sl*16];
        }
        #pragma unroll
        for (int mi = 0; mi < 4; ++mi)
          #pragma unroll
          for (int n = 0; n < 4; ++n)
            acc[mh*4+mi][n] = __builtin_amdgcn_mfma_i32_16x16x64_i8(
                a[mi], b[n], acc[mh*4+mi][n], 0, 0, 0);
      }
    }
    __syncthreads();               // drains prefetch; protects buf reuse
    cur ^= 1;
  }

  if constexpr (sizeof(OUT_T) == 2){
    // counts tile -> LDS (scatter), then coalesced 16B streams to global
    unsigned short* Ct = (unsigned short*)smem;
    #pragma unroll
    for (int m = 0; m < 8; ++m)
      #pragma unroll
      for (int n = 0; n < 4; ++n){
        int lr = wr*128 + m*16 + fq*4;
        int lc = wc*64 + n*16 + fr;
        #pragma unroll
        for (int j = 0; j < 4; ++j)
          Ct[(lr + j)*256 + lc] = (unsigned short)acc[m][n][j];
      }
    __syncthreads();
    #pragma unroll
    for (int q = 0; q < 16; ++q){
      int idx = q*8192 + tid*16;   // byte offset into the 128 KB tile
      int lr = idx >> 9;           // 512 B per local row
      int lcb = idx & 511;
      char* gp = (char*)(out + ((size_t)(brow + lr))*N_DIM + bcol) + lcb;
      *(uint4*)gp = *(const uint4*)&smem[idx];
    }
  } else {
    #pragma unroll
    for (int m = 0; m < 8; ++m)
      #pragma unroll
      for (int n = 0; n < 4; ++n){
        int row = brow + wr*128 + m*16 + fq*4;
        int col = bcol + wc*64 + n*16 + fr;
        #pragma unroll
        for (int j = 0; j < 4; ++j)
          out[((size_t)(row + j))*N_DIM + col] = (OUT_T)acc[m][n][j];
      }
  }
}

// ---------------- fallback GEMM (tiny ws): bf16 reg-staged ------------------
__global__ __launch_bounds__(256) void gemm_fb_kernel(const float* __restrict__ X,
                                                      const float* __restrict__ Cn,
                                                      float* __restrict__ out){
  __shared__ ushort_t As[128*32];
  __shared__ ushort_t Bs[128*32];
  int tid = threadIdx.x;
  int bn = blockIdx.x & 31, bm = blockIdx.x >> 5;
  int brow = bm * 128, bcol = bn * 128;
  int lane = tid & 63, w = tid >> 6;
  int wr = w >> 1, wc = w & 1;
  int fr = lane & 15, fq = lane >> 4;
  f32x4 acc[4][4];
  for (int m = 0; m < 4; ++m)
    for (int n = 0; n < 4; ++n)
      acc[m][n] = (f32x4){0.f, 0.f, 0.f, 0.f};
  int r2 = tid >> 1, h = tid & 1;
  int kr = tid >> 3, seg = tid & 7;
  for (int kk = 0; kk < K_DIM; kk += 32){
    __syncthreads();
    const float* ga = X + ((size_t)(brow + r2))*K_DIM + kk + h*16;
    unsigned pk[8];
    for (int q = 0; q < 4; ++q){
      float4 f = *(const float4*)(ga + q*4);
      pk[q*2]   = (unsigned)f2bf(f.x) | ((unsigned)f2bf(f.y) << 16);
      pk[q*2+1] = (unsigned)f2bf(f.z) | ((unsigned)f2bf(f.w) << 16);
    }
    uint4 u0; u0.x = pk[0]; u0.y = pk[1]; u0.z = pk[2]; u0.w = pk[3];
    uint4 u1; u1.x = pk[4]; u1.y = pk[5]; u1.z = pk[6]; u1.w = pk[7];
    *(uint4*)&As[r2*32 + h*16]     = u0;
    *(uint4*)&As[r2*32 + h*16 + 8] = u1;
    const float* gb = Cn + ((size_t)(kk + kr))*N_DIM + bcol + seg*16;
    for (int q = 0; q < 4; ++q){
      float4 f = *(const float4*)(gb + q*4);
      Bs[(seg*16 + q*4 + 0)*32 + kr] = f2bf(f.x);
      Bs[(seg*16 + q*4 + 1)*32 + kr] = f2bf(f.y);
      Bs[(seg*16 + q*4 + 2)*32 + kr] = f2bf(f.z);
      Bs[(seg*16 + q*4 + 3)*32 + kr] = f2bf(f.w);
    }
    __syncthreads();
    short8 a[4], b[4];
    for (int m = 0; m < 4; ++m) a[m] = *(const short8*)&As[(wr*64 + m*16 + fr)*32 + fq*8];
    for (int n = 0; n < 4; ++n) b[n] = *(const short8*)&Bs[(wc*64 + n*16 + fr)*32 + fq*8];
    for (int m = 0; m < 4; ++m)
      for (int n = 0; n < 4; ++n)
        acc[m][n] = __builtin_amdgcn_mfma_f32_16x16x32_bf16(a[m], b[n], acc[m][n], 0, 0, 0);
  }
  for (int m = 0; m < 4; ++m)
    for (int n = 0; n < 4; ++n){
      int row = brow + wr*64 + m*16 + fq*4;
      int col = bcol + wc*64 + n*16 + fr;
      for (int j = 0; j < 4; ++j)
        out[((size_t)(row + j))*N_DIM + col] = acc[m][n][j];
    }
}

// ---------------- per-row exact top-82 -> one-hot ---------------------------
// Two-level radix select on the DOUBLE bit pattern (positive doubles: value
// order == u64 bit order). Tie-break: lower index wins.
__device__ __forceinline__ void find_bin(unsigned* hist, unsigned* wtot,
                                         int* pB, int* pK, int tid, int Kt){
  int lane = tid & 63, w = tid >> 6;
  unsigned s = 0;
  #pragma unroll
  for (int b = 0; b < 16; ++b) s += hist[tid*16 + b];
  unsigned S = s;
  #pragma unroll
  for (int off = 1; off < 64; off <<= 1){
    unsigned T = __shfl_down(S, off, 64);
    if (lane + off < 64) S += T;
  }
  if (lane == 0) wtot[w] = S;          // whole-wave total (suffix at lane 0)
  __syncthreads();
  unsigned above = 0;
  for (int w2 = w + 1; w2 < 4; ++w2) above += wtot[w2];
  unsigned St = S + above;             // count with bin >= tid*16
  unsigned Sn = St - s;                // count with bin >= (tid+1)*16
  if (St >= (unsigned)Kt && Sn < (unsigned)Kt){   // exactly one thread
    unsigned cum = Sn;
    for (int b = 15; b >= 0; --b){
      unsigned hb = hist[tid*16 + b];
      cum += hb;
      if (cum >= (unsigned)Kt){ *pB = tid*16 + b; *pK = Kt - (int)(cum - hb); break; }
    }
  }
  __syncthreads();
}

template<typename CT>
__global__ __launch_bounds__(256) void topk_kernel(const CT* __restrict__ cnt,
                                                   float* __restrict__ outp,
                                                   const double* __restrict__ boost){
  __shared__ unsigned hist[4096];
  __shared__ unsigned wtot[4];
  __shared__ int sB, sK, sB2, sK2, scnt, sTi;
  __shared__ u64 sTv;
  __shared__ u64 cbits[256];
  __shared__ int cidx[256];
  int tid = threadIdx.x;
  const CT* rp = cnt + (size_t)blockIdx.x * N_DIM;
  float* wp = outp + (size_t)blockIdx.x * N_DIM;

  double v[16];
  unsigned bin[16];
  #pragma unroll
  for (int g = 0; g < 4; ++g){
    int c0 = g*1024 + tid*4;
    double4 bf = *(const double4*)&boost[c0];
    if constexpr (sizeof(CT) == 2){
      ushort4 f = *(const ushort4*)&rp[c0];
      v[g*4+0] = (double)f.x * bf.x;
      v[g*4+1] = (double)f.y * bf.y;
      v[g*4+2] = (double)f.z * bf.z;
      v[g*4+3] = (double)f.w * bf.w;
    } else {
      float4 f = *(const float4*)&rp[c0];
      v[g*4+0] = (double)f.x * bf.x;
      v[g*4+1] = (double)f.y * bf.y;
      v[g*4+2] = (double)f.z * bf.z;
      v[g*4+3] = (double)f.w * bf.w;
    }
  }
  #pragma unroll
  for (int e = 0; e < 16; ++e)
    bin[e] = (unsigned)(((u64)__double_as_longlong(v[e])) >> 51) & 4095u;

  #pragma unroll
  for (int i = 0; i < 16; ++i) hist[tid + 256*i] = 0u;
  __syncthreads();
  #pragma unroll
  for (int e = 0; e < 16; ++e) atomicAdd(&hist[bin[e]], 1u);
  __syncthreads();

  find_bin(hist, wtot, &sB, &sK, tid, TOPK);       // L1: boundary bin B, rank k1
  int B = sB, k1 = sK;

  #pragma unroll
  for (int i = 0; i < 16; ++i) hist[tid + 256*i] = 0u;
  if (tid == 0) scnt = 0;
  __syncthreads();
  #pragma unroll
  for (int e = 0; e < 16; ++e){
    if (bin[e] == (unsigned)B){
      unsigned b2 = (unsigned)(((u64)__double_as_longlong(v[e])) >> 39) & 4095u;
      atomicAdd(&hist[b2], 1u);
    }
  }
  __syncthreads();

  find_bin(hist, wtot, &sB2, &sK2, tid, k1);       // L2: sub-bin B2, rank k2
  int B2 = sB2, k2 = sK2;

  #pragma unroll
  for (int e = 0; e < 16; ++e){
    if (bin[e] == (unsigned)B){
      u64 ub = (u64)__double_as_longlong(v[e]);
      if ((unsigned)((ub >> 39) & 4095u) == (unsigned)B2){
        int pos = atomicAdd(&scnt, 1);
        if (pos < 256){
          int g = e >> 2, j = e & 3;
          cbits[pos] = ub;
          cidx[pos] = g*1024 + tid*4 + j;
        }
      }
    }
  }
  __syncthreads();
  int Csz = scnt; if (Csz > 256) Csz = 256;
  for (int i = tid; i < Csz; i += 256){
    u64 bi = cbits[i]; int xi = cidx[i];
    int rk = 0;
    for (int j2 = 0; j2 < Csz; ++j2){
      u64 bj = cbits[j2];
      rk += (int)((bj > bi) || (bj == bi && cidx[j2] < xi));
    }
    if (rk == k2 - 1){ sTv = bi; sTi = xi; }       // the exact K-th element
  }
  __syncthreads();
  double Tv = __longlong_as_double((long long)sTv);
  int Ti = sTi;
  #pragma unroll
  for (int g = 0; g < 4; ++g){
    int c0 = g*1024 + tid*4;
    float4 o;
    o.x = (v[g*4+0] > Tv || (v[g*4+0] == Tv && (c0+0) <= Ti)) ? 1.0f : 0.0f;
    o.y = (v[g*4+1] > Tv || (v[g*4+1] == Tv && (c0+1) <= Ti)) ? 1.0f : 0.0f;
    o.z = (v[g*4+2] > Tv || (v[g*4+2] == Tv && (c0+2) <= Ti)) ? 1.0f : 0.0f;
    o.w = (v[g*4+3] > Tv || (v[g*4+3] == Tv && (c0+3) <= Ti)) ? 1.0f : 0.0f;
    *(float4*)&wp[c0] = o;
  }
}

extern "C" void kernel_launch(void* const* d_in, const int* in_sizes, int n_in,
                              void* d_out, int out_size, void* d_ws, size_t ws_size,
                              hipStream_t stream){
  (void)in_sizes; (void)n_in; (void)out_size;
  const float* X   = (const float*)d_in[0];   // x [8192][2048]
  const float* Cn  = (const float*)d_in[1];   // connection [2048][4096]
  const float* avg = (const float*)d_in[2];   // avg_activation [4096]
  float* out = (float*)d_out;                 // [8192][4096]
  char* ws = (char*)d_ws;

  double* boost = (double*)ws;                                          // 32 KB
  const size_t offA = 65536;
  unsigned char* A8 = (unsigned char*)(ws + offA);                      // 16 MB
  unsigned char* B8 = (unsigned char*)(ws + offA + (size_t)16777216);   //  8 MB
  unsigned short* CNT = (unsigned short*)(ws + offA + (size_t)25165824);// 64 MB
  const size_t need_mid  = offA + (size_t)25165824;
  const size_t need_full = need_mid + (size_t)67108864;

  boost_kernel<<<dim3(1), dim3(256), 0, stream>>>(avg, boost);
  if (ws_size >= need_full){
    convA8_kernel<<<dim3(4096), dim3(256), 0, stream>>>(X, A8);
    convB8_kernel<<<dim3(8192), dim3(256), 0, stream>>>(Cn, B8);
    gemm2_kernel<unsigned short><<<dim3(512), dim3(512), 0, stream>>>(A8, B8, CNT);
    topk_kernel<unsigned short><<<dim3(8192), dim3(256), 0, stream>>>(CNT, out, boost);
  } else if (ws_size >= need_mid){
    convA8_kernel<<<dim3(4096), dim3(256), 0, stream>>>(X, A8);
    convB8_kernel<<<dim3(8192), dim3(256), 0, stream>>>(Cn, B8);
    gemm2_kernel<float><<<dim3(512), dim3(512), 0, stream>>>(A8, B8, out);
    topk_kernel<float><<<dim3(8192), dim3(256), 0, stream>>>(out, out, boost);
  } else {
    gemm_fb_kernel<<<dim3(2048), dim3(256), 0, stream>>>(X, Cn, out);
    topk_kernel<float><<<dim3(8192), dim3(256), 0, stream>>>(out, out, boost);
  }
}